// Round 10
// baseline (448.270 us; speedup 1.0000x reference)
//
#include <hip/hip_runtime.h>
#include <hip/hip_bf16.h>

#define B_ 8
#define T_ 2048
#define C_ 512
#define H_ 16
#define HS_ 32
#define BT_ (B_*T_)   // 16384 tokens
#define CL_ 64        // scan chunk length
#define NC_ (T_/CL_)  // 32 chunks
#define STF_ 1056     // floats per (bh,chunk) state: 1024 S + 32 P
#define WSZ_ 262144   // elements per 512x512 weight (2^18)

typedef __hip_bfloat16 bf16;
typedef __attribute__((ext_vector_type(8))) short short8;
typedef __attribute__((ext_vector_type(4))) short short4v;
typedef __attribute__((ext_vector_type(8))) _Float16 half8;
typedef __attribute__((ext_vector_type(4))) float f32x4;

__device__ __forceinline__ float b2f(bf16 v) { return __bfloat162float(v); }
__device__ __forceinline__ bf16 f2b(float v) { return __float2bfloat16(v); }
// raw-bits helpers for vectorized bf16 handling
__device__ __forceinline__ float s2f(short s) {
  unsigned u = ((unsigned)(unsigned short)s) << 16;
  return __builtin_bit_cast(float, u);
}
__device__ __forceinline__ short f2s(float f) {
  bf16 b = f2b(f);
  return __builtin_bit_cast(short, b);
}
// fp16 raw-bits helpers
__device__ __forceinline__ short f2h(float f) {
  _Float16 h = (_Float16)f;
  return __builtin_bit_cast(short, h);
}

// unified 16x16x32 MFMA over raw short8 operands: FP16=0 -> bf16, 1 -> f16.
template<int FP16>
__device__ __forceinline__ f32x4 mfma16(short8 a, short8 b, f32x4 c) {
  if constexpr (FP16)
    return __builtin_amdgcn_mfma_f32_16x16x32_f16(
        __builtin_bit_cast(half8, a), __builtin_bit_cast(half8, b), c, 0, 0, 0);
  else
    return __builtin_amdgcn_mfma_f32_16x16x32_bf16(a, b, c, 0, 0, 0);
}

// async global->LDS 16B direct copy. LDS dst must be wave-uniform base +
// lane*16 — all call sites use &LDS[tid(+k)] which is.
__device__ __forceinline__ void gl2lds(const void* g, void* l) {
  __builtin_amdgcn_global_load_lds(
      (const __attribute__((address_space(1))) void*)g,
      (__attribute__((address_space(3))) void*)l, 16, 0, 0);
}

// ---------------------------------------------------------------------------
// prep_combo: (a) xxx = x + (xshift-x)*maa_x (bf16), (b) fp16 convert of the
// five 512x512 weights, (c) transpose+pad w1 -> [192][512] bf16 and
// wd1 -> [64][512] fp16, (d) transpose+pad w2 -> [512][192] bf16.
// ---------------------------------------------------------------------------
__global__ __launch_bounds__(256) void prep_combo_kernel(
    const float* __restrict__ x, const float* __restrict__ tmx,
    const float* __restrict__ Wr, const float* __restrict__ Wk,
    const float* __restrict__ Wv, const float* __restrict__ Wg,
    const float* __restrict__ Wo, const float* __restrict__ w1,
    const float* __restrict__ wd1, const float* __restrict__ w2,
    bf16* __restrict__ xxx, short* __restrict__ Wrb, short* __restrict__ Wkb,
    short* __restrict__ Wvb, short* __restrict__ Wgb, short* __restrict__ Wob,
    bf16* __restrict__ w1p, short* __restrict__ wd1p, bf16* __restrict__ w2p) {
  int idx = blockIdx.x * 256 + threadIdx.x;
  if (idx < BT_ * C_) {                       // token-shift mix input
    int c = idx & (C_ - 1);
    int t = (idx >> 9) & (T_ - 1);
    float xc = x[idx];
    float xp = (t == 0) ? 0.f : x[idx - C_];
    xxx[idx] = f2b(xc + (xp - xc) * tmx[c]);
    return;
  }
  idx -= BT_ * C_;
  if (idx < 5 * WSZ_) {                       // weight fp16 convert
    int w = idx >> 18;
    int i = idx & (WSZ_ - 1);
    const float* src = (w == 0) ? Wr : (w == 1) ? Wk : (w == 2) ? Wv
                     : (w == 3) ? Wg : Wo;
    short* dst = (w == 0) ? Wrb : (w == 1) ? Wkb : (w == 2) ? Wvb
               : (w == 3) ? Wgb : Wob;
    dst[i] = f2h(src[i]);
    return;
  }
  idx -= 5 * WSZ_;
  if (idx < 192 * 512) {                      // w1^T padded to 192 rows (bf16)
    int n = idx >> 9, k = idx & (C_ - 1);
    w1p[idx] = f2b(n < 160 ? w1[k * 160 + n] : 0.f);
    return;
  }
  idx -= 192 * 512;
  if (idx < 64 * 512) {                       // wd1^T [64][512] (fp16)
    int n = idx >> 9, k = idx & (C_ - 1);
    wd1p[idx] = f2h(wd1[k * 64 + n]);
    return;
  }
  idx -= 64 * 512;
  {                                           // w2^T padded [512][192] (bf16)
    int c = idx / 192, n = idx - c * 192;     // n = f*32+d
    w2p[idx] = f2b(n < 160 ? w2[(size_t)n * C_ + c] : 0.f);
  }
}
#define PREP_N_ ((BT_*C_ + 5*WSZ_ + 192*512 + 64*512 + 512*192) / 256) // 38784

// ---------------------------------------------------------------------------
// MFMA GEMM (256 thr): O = act(A @ Bw^T). BM=128. Single-buffer m97 structure.
// Used for the small GEMMs (mix5p BN=64, h1 BN=64).
// FP16: 0 = bf16 operands, 1 = fp16. MODE: 0 bf16; 1 +silu; 2 fp32; 3 +tanh.
// ---------------------------------------------------------------------------
template<int BN, int MODE, int FP16, int BKT>
__global__ __launch_bounds__(256) void mfma_gemm_kernel(
    const short* __restrict__ A, const short* __restrict__ Bw,
    void* __restrict__ O, int N) {
  constexpr int BM = 128;
  constexpr int KC = BKT / 32;               // 32-wide sub-tiles per K-step
  constexpr int AE1 = BM * 32 / 8;           // 512 short8 per sub-tile
  constexpr int BE1 = BN * 32 / 8;
  __shared__ short8 Asm[KC * AE1];
  __shared__ short8 Bsm[KC * BE1];
  const int tid = threadIdx.x;
  const int lane = tid & 63;
  const int wave = tid >> 6;
  const int m0 = blockIdx.x * BM;
  const int n0 = blockIdx.y * BN;
  const int wm = (BN == 128) ? (wave >> 1) * 64 : wave * 32;
  const int wn = (BN == 128) ? (wave & 1) * 64 : 0;
  constexpr int MT = (BN == 128) ? 4 : 2;
  constexpr int NT = 4;
  f32x4 acc[MT][NT] = {};
  const int e0 = tid, e1 = tid + 256;
  const int r0 = ((e0 >> 6) << 4) | (e0 & 15), q0 = (e0 >> 4) & 3;
  const int r1 = ((e1 >> 6) << 4) | (e1 & 15), q1 = (e1 >> 4) & 3;
  const unsigned short* Au = (const unsigned short*)A;
  const unsigned short* Bu = (const unsigned short*)Bw;
  for (int k0 = 0; k0 < C_; k0 += BKT) {
    __syncthreads();   // all ds_reads of previous iteration complete
    #pragma unroll
    for (int kc = 0; kc < KC; ++kc) {
      int kk = k0 + kc * 32;
      gl2lds(&Au[(size_t)(m0 + r0) * C_ + kk + q0 * 8], &Asm[kc * AE1 + e0]);
      gl2lds(&Au[(size_t)(m0 + r1) * C_ + kk + q1 * 8], &Asm[kc * AE1 + e1]);
      gl2lds(&Bu[(size_t)(n0 + r0) * C_ + kk + q0 * 8], &Bsm[kc * BE1 + e0]);
      if constexpr (BN == 128)
        gl2lds(&Bu[(size_t)(n0 + r1) * C_ + kk + q1 * 8], &Bsm[kc * BE1 + e1]);
    }
    __syncthreads();   // implicit vmcnt(0) drain -> LDS tile ready
    #pragma unroll
    for (int kc = 0; kc < KC; ++kc) {
      short8 af[MT], bh[NT];
      #pragma unroll
      for (int mt = 0; mt < MT; ++mt)
        af[mt] = Asm[kc * AE1 + ((wm >> 4) + mt) * 64 + lane];
      #pragma unroll
      for (int nt = 0; nt < NT; ++nt)
        bh[nt] = Bsm[kc * BE1 + ((wn >> 4) + nt) * 64 + lane];
      #pragma unroll
      for (int mt = 0; mt < MT; ++mt)
        #pragma unroll
        for (int nt = 0; nt < NT; ++nt)
          acc[mt][nt] = mfma16<FP16>(af[mt], bh[nt], acc[mt][nt]);
    }
  }
  const int col = lane & 15, qr = lane >> 4;
  #pragma unroll
  for (int mt = 0; mt < MT; ++mt) {
    int mrow = m0 + wm + mt * 16 + qr * 4;
    #pragma unroll
    for (int nt = 0; nt < NT; ++nt) {
      int nc = n0 + wn + nt * 16 + col;
      #pragma unroll
      for (int r = 0; r < 4; ++r) {
        float v = acc[mt][nt][r];
        if (MODE == 1) v = v / (1.f + __expf(-v));
        if (MODE == 3) v = tanhf(v);
        size_t oi = (size_t)(mrow + r) * N + nc;
        if (MODE == 2) ((float*)O)[oi] = v;
        else           ((bf16*)O)[oi] = f2b(v);
      }
    }
  }
}

// ---------------------------------------------------------------------------
// gemm_stream: NO-LDS, NO-BARRIER fp16 GEMM for tall-skinny M=16384, K=N=512.
// Block = 8 waves over one 64-row stripe; wave w owns cols [w*64, w*64+64).
// Per K-chunk each wave direct-loads MFMA fragments: af[4] (same addrs for
// all 8 waves -> L1 broadcast; A read ONCE per GEMM, L3-resident) and bh[4]
// (B is 0.5MB fp16, L2-hot). Zero synchronization -> loads pipeline freely
// across chunks; no vmcnt(0) drain exists (R4-R8 showed the drain-per-K-step
// LDS structure is immovable at ~380 TF for this shape).
// MODE: 0 bf16 out; 1 bf16+silu; 2 fp32 out. Output stride C_.
// ---------------------------------------------------------------------------
template<int MODE>
__device__ __forceinline__ void gemm_stream_body(
    const short* __restrict__ A, const short* __restrict__ Bw,
    void* __restrict__ O) {
  const int tid = threadIdx.x;
  const int lane = tid & 63;
  const int wave = tid >> 6;               // 0..7
  const int m0 = blockIdx.x * 64;
  const int n0 = wave * 64;
  const int fl = lane & 15, q = lane >> 4;
  constexpr int MT = 4, NT = 4;
  f32x4 acc[MT][NT] = {};
  const unsigned short* Au = (const unsigned short*)A;
  const unsigned short* Bu = (const unsigned short*)Bw;
  #pragma unroll 4
  for (int k0 = 0; k0 < C_; k0 += 32) {
    short8 af[MT], bh[NT];
    #pragma unroll
    for (int mt = 0; mt < MT; ++mt)
      af[mt] = *(const short8*)&Au[(size_t)(m0 + mt * 16 + fl) * C_ + k0 + q * 8];
    #pragma unroll
    for (int nt = 0; nt < NT; ++nt)
      bh[nt] = *(const short8*)&Bu[(size_t)(n0 + nt * 16 + fl) * C_ + k0 + q * 8];
    #pragma unroll
    for (int mt = 0; mt < MT; ++mt)
      #pragma unroll
      for (int nt = 0; nt < NT; ++nt)
        acc[mt][nt] = mfma16<1>(af[mt], bh[nt], acc[mt][nt]);
  }
  const int col = lane & 15, qr = lane >> 4;
  #pragma unroll
  for (int mt = 0; mt < MT; ++mt) {
    int mrow = m0 + mt * 16 + qr * 4;
    #pragma unroll
    for (int nt = 0; nt < NT; ++nt) {
      int nc = n0 + nt * 16 + col;
      #pragma unroll
      for (int r = 0; r < 4; ++r) {
        float v = acc[mt][nt][r];
        if (MODE == 1) v = v / (1.f + __expf(-v));
        size_t oi = (size_t)(mrow + r) * C_ + nc;
        if (MODE == 2) ((float*)O)[oi] = v;
        else           ((bf16*)O)[oi] = f2b(v);
      }
    }
  }
}

// the four independent fp16 projections in one launch (blockIdx.z selects)
__global__ __launch_bounds__(512) void proj4_gemm_kernel(
    const short* __restrict__ A0, const short* __restrict__ B0, bf16* __restrict__ O0,
    const short* __restrict__ A1, const short* __restrict__ B1, bf16* __restrict__ O1,
    const short* __restrict__ A2, const short* __restrict__ B2, bf16* __restrict__ O2,
    const short* __restrict__ A3, const short* __restrict__ B3, bf16* __restrict__ O3) {
  const int zz = blockIdx.z;
  const short* A  = (zz == 0) ? A0 : (zz == 1) ? A1 : (zz == 2) ? A2 : A3;
  const short* Bw = (zz == 0) ? B0 : (zz == 1) ? B1 : (zz == 2) ? B2 : B3;
  bf16* O         = (zz == 0) ? O0 : (zz == 1) ? O1 : (zz == 2) ? O2 : O3;
  if (zz == 3) gemm_stream_body<1>(A, Bw, O);
  else         gemm_stream_body<0>(A, Bw, O);
}

// output projection (fp32 out)
__global__ __launch_bounds__(512) void wo_gemm_kernel(
    const short* __restrict__ A, const short* __restrict__ Bw,
    float* __restrict__ O) {
  gemm_stream_body<2>(A, Bw, O);
}

// ---------------------------------------------------------------------------
// mix_mfma (verified round 0): five K=32 GEMMs via MFMA fused with the
// elementwise epilogue x_f = x + (xshift-x)*(tm_f + m_f). Outputs fp16.
// ---------------------------------------------------------------------------
__global__ __launch_bounds__(256) void mix_mfma_kernel(
    const bf16* __restrict__ mix5, const bf16* __restrict__ w2p,
    const float* __restrict__ x,
    const float* __restrict__ tmw, const float* __restrict__ tmk,
    const float* __restrict__ tmv, const float* __restrict__ tmr,
    const float* __restrict__ tmg,
    short* __restrict__ xw, short* __restrict__ xk, short* __restrict__ xv,
    short* __restrict__ xr, short* __restrict__ xg) {
  constexpr int LDP = 200;
  __shared__ __align__(16) unsigned short Asm[64 * LDP];
  __shared__ __align__(16) unsigned short Bsm[64 * LDP];
  const int tid = threadIdx.x;
  const int row0 = blockIdx.x * 64;
  const int col0 = blockIdx.y * 64;
  const unsigned short* Au = (const unsigned short*)mix5;
  const unsigned short* Bu = (const unsigned short*)w2p;
  #pragma unroll
  for (int e0 = 0; e0 < 64 * 20; e0 += 256) {
    int e = e0 + tid;
    int rr = e / 20, p = e - rr * 20;
    *(short8*)&Asm[rr * LDP + p * 8] =
        *(const short8*)&Au[(size_t)(row0 + rr) * 192 + p * 8];
    *(short8*)&Bsm[rr * LDP + p * 8] =
        *(const short8*)&Bu[(size_t)(col0 + rr) * 192 + p * 8];
  }
  __syncthreads();
  const int lane = tid & 63, wave = tid >> 6;
  const int fl = lane & 15, q = lane >> 4;
  short8 af[5];
  #pragma unroll
  for (int f = 0; f < 5; ++f)
    af[f] = *(const short8*)&Asm[(wave * 16 + fl) * LDP + f * 32 + q * 8];
  f32x4 acc[4][5] = {};
  #pragma unroll
  for (int nt = 0; nt < 4; ++nt)
    #pragma unroll
    for (int f = 0; f < 5; ++f) {
      short8 bfr = *(const short8*)&Bsm[(nt * 16 + fl) * LDP + f * 32 + q * 8];
      acc[nt][f] = __builtin_amdgcn_mfma_f32_16x16x32_bf16(
          af[f], bfr, acc[nt][f], 0, 0, 0);
    }
  #pragma unroll
  for (int nt = 0; nt < 4; ++nt) {
    int cc = col0 + nt * 16 + fl;
    float vw = tmw[cc], vk = tmk[cc], vv = tmv[cc], vr = tmr[cc],
          vg = tmg[cc];
    #pragma unroll
    for (int r = 0; r < 4; ++r) {
      int rr = row0 + wave * 16 + q * 4 + r;
      size_t idx = (size_t)rr * C_ + cc;
      float xc = x[idx];
      float xx = (((rr & (T_ - 1)) == 0) ? 0.f : x[idx - C_]) - xc;
      xw[idx] = f2h(xc + xx * (vw + acc[nt][0][r]));
      xk[idx] = f2h(xc + xx * (vk + acc[nt][1][r]));
      xv[idx] = f2h(xc + xx * (vv + acc[nt][2][r]));
      xr[idx] = f2h(xc + xx * (vr + acc[nt][3][r]));
      xg[idx] = f2h(xc + xx * (vg + acc[nt][4][r]));
    }
  }
}

// ---------------------------------------------------------------------------
// decay (unchanged, verified): w = td + h1 @ Wd2 (K=64); ee = exp(w) bf16.
// ---------------------------------------------------------------------------
__global__ __launch_bounds__(512) void decay_kernel(
    const bf16* __restrict__ h1, const float* __restrict__ wd2,
    const float* __restrict__ tdecay, bf16* __restrict__ ee) {
  __shared__ float Hs[8][64];
  int row0 = blockIdx.x * 8;
  {
    int e = threadIdx.x;
    Hs[e >> 6][e & 63] = b2f(h1[(size_t)(row0 + (e >> 6)) * 64 + (e & 63)]);
  }
  __syncthreads();
  int c = threadIdx.x;
  float acc[8] = {0.f,0.f,0.f,0.f,0.f,0.f,0.f,0.f};
  for (int j = 0; j < 64; ++j) {
    float wv = wd2[j * C_ + c];
    #pragma unroll
    for (int r = 0; r < 8; ++r) acc[r] += Hs[r][j] * wv;
  }
  float td = tdecay[c];
  #pragma unroll
  for (int r = 0; r < 8; ++r)
    ee[(size_t)(row0 + r) * C_ + c] = f2b(expf(td + acc[r]));
}

// ---------------------------------------------------------------------------
// WKV6 chunked scan — 4-wave form, vectorized loads (verified round 3).
// ---------------------------------------------------------------------------
__global__ __launch_bounds__(256) void wkv_partial_mfma(
    const bf16* __restrict__ k, const bf16* __restrict__ v,
    const bf16* __restrict__ ee, float* __restrict__ st) {
  __shared__ __align__(16) char smem[17536];
  float* Lm  = (float*)smem;              // [65][32] floats, 8320 B
  bf16*  K2T = (bf16*)(smem + 8320);      // [32][72]
  bf16*  VT  = (bf16*)(smem + 12928);     // [32][72]
  bf16*  Eb  = K2T;                       // [64][32] scratch (dead pre-stage)
  int g = blockIdx.x;
  int bh = g >> 5, c = g & (NC_ - 1);
  int b = bh >> 4, h = bh & 15;
  const int tid = threadIdx.x;
  const int lane = tid & 63, wave = tid >> 6;
  const int tl = lane >> 3;              // 0..7
  const int c4 = (lane & 7) * 4;
  size_t gbase = (size_t)b * T_ * C_ + (size_t)(c * CL_) * C_ + h * HS_;
  const short* ku = (const short*)k;
  const short* vu = (const short*)v;
  const short* eu = (const short*)ee;
  #pragma unroll
  for (int it = 0; it < 2; ++it) {       // ee tile, 8B per thread per iter
    int e4 = it * 256 + tid;             // 0..511
    int row = e4 >> 3, cc = (e4 & 7) * 4;
    short4v ev = *(const short4v*)&eu[gbase + (size_t)row * C_ + cc];
    *(short4v*)&((short*)Eb)[row * 32 + cc] = ev;
  }
  short4v k4[2], v4[2];
  #pragma unroll
  for (int it2 = 0; it2 < 2; ++it2) {
    int t = wave * 16 + it2 * 8 + tl;
    k4[it2] = *(const short4v*)&ku[gbase + (size_t)t * C_ + c4];
    v4[it2] = *(const short4v*)&vu[gbase + (size_t)t * C_ + c4];
  }
  __syncthreads();
  if (tid < 32) {
    float L = 0.f;
    for (int t = 0; t < CL_; ++t) {
      Lm[t * 32 + tid] = L;
      L -= b2f(Eb[t * 32 + tid]);
    }
    Lm[64 * 32 + tid] = L;
  }
  __syncthreads();
  f32x4 Ltot4 = *(const f32x4*)&Lm[64 * 32 + c4];
  #pragma unroll
  for (int it2 = 0; it2 < 2; ++it2) {
    int t = wave * 16 + it2 * 8 + tl;
    f32x4 Lt14 = *(const f32x4*)&Lm[(t + 1) * 32 + c4];
    #pragma unroll
    for (int j = 0; j < 4; ++j) {
      ((short*)K2T)[(c4 + j) * 72 + t] =
          f2s(s2f(k4[it2][j]) * __expf(Ltot4[j] - Lt14[j]));
      ((short*)VT)[(c4 + j) * 72 + t] = v4[it2][j];
    }
  }
  __syncthreads();
  const int fl = lane & 15, q = lane >> 4;
  const int mt = wave >> 1, nt = wave & 1;
  f32x4 accS = {};
  #pragma unroll
  for (int kc = 0; kc < 2; ++kc) {
    short8 av = *(const short8*)(VT + (mt * 16 + fl) * 72 + kc * 32 + q * 8);
    short8 bk = *(const short8*)(K2T + (nt * 16 + fl) * 72 + kc * 32 + q * 8);
    accS = __builtin_amdgcn_mfma_f32_16x16x32_bf16(av, bk, accS, 0, 0, 0);
  }
  size_t sbase = (size_t)g * STF_;
  #pragma unroll
  for (int r = 0; r < 4; ++r)
    st[sbase + (size_t)(mt * 16 + q * 4 + r) * 32 + nt * 16 + fl] = accS[r];
  if (tid < 32) st[sbase + 1024 + tid] = __expf(Lm[64 * 32 + tid]);
}

// ---------------------------------------------------------------------------
// stitch: serial chunk recurrence R = P*R + Sc per (bh), depth-1 software
// pipeline (verified round 3). Incoming state for chunk c emitted bf16 hi/lo
// into dead S-region of slot c-1.
// ---------------------------------------------------------------------------
__global__ __launch_bounds__(64) void wkv_stitch_kernel(float* __restrict__ st) {
  int bh = blockIdx.x;
  int lane = threadIdx.x;
  int i = lane & 31, half = lane >> 5;
  float R[16];
  #pragma unroll
  for (int jj = 0; jj < 16; ++jj) R[jj] = 0.f;
  size_t s0 = (size_t)bh * NC_ * STF_;
  const int off = i * 32 + (half << 4);
  const int poff = 1024 + (half << 4);
  f32x4 Sc[4], Pj[4];
  {
    const f32x4* sp = (const f32x4*)(st + s0 + off);
    const f32x4* pp = (const f32x4*)(st + s0 + poff);
    #pragma unroll
    for (int q = 0; q < 4; ++q) { Sc[q] = sp[q]; Pj[q] = pp[q]; }
  }
  for (int c = 0; c < NC_; ++c) {
    size_t s = s0 + (size_t)c * STF_;
    f32x4 Sn[4], Pn[4];
    if (c + 1 < NC_) {
      const f32x4* sp = (const f32x4*)(st + s + STF_ + off);
      const f32x4* pp = (const f32x4*)(st + s + STF_ + poff);
      #pragma unroll
      for (int q = 0; q < 4; ++q) { Sn[q] = sp[q]; Pn[q] = pp[q]; }
    }
    if (c > 0) {
      __align__(16) short hi16[16], lo16[16];
      #pragma unroll
      for (int jj = 0; jj < 16; ++jj) {
        short hb = f2s(R[jj]);
        hi16[jj] = hb;
        lo16[jj] = f2s(R[jj] - s2f(hb));
      }
      short* sb = (short*)(st + s - STF_);
      *(short8*)&sb[off]         = *(const short8*)&hi16[0];
      *(short8*)&sb[off + 8]     = *(const short8*)&hi16[8];
      *(short8*)&sb[1024 + off]     = *(const short8*)&lo16[0];
      *(short8*)&sb[1024 + off + 8] = *(const short8*)&lo16[8];
    }
    #pragma unroll
    for (int q = 0; q < 4; ++q)
      #pragma unroll
      for (int j = 0; j < 4; ++j)
        R[q * 4 + j] = fmaf(Pj[q][j], R[q * 4 + j], Sc[q][j]);
    if (c + 1 < NC_) {
      #pragma unroll
      for (int q = 0; q < 4; ++q) { Sc[q] = Sn[q]; Pj[q] = Pn[q]; }
    }
  }
}

// ---------------------------------------------------------------------------
// wkv_final: 4-wave + fused groupnorm + vectorized staging (verified round 3).
// S fragments direct from stitched bf16 hi/lo state (slot g-1). z fp16.
// ---------------------------------------------------------------------------
__global__ __launch_bounds__(256) void wkv_final_mfma(
    const bf16* __restrict__ r, const bf16* __restrict__ k,
    const bf16* __restrict__ v, const bf16* __restrict__ ee,
    const float* __restrict__ faaaa, const float* __restrict__ st,
    const bf16* __restrict__ gg, const float* __restrict__ lnw,
    const float* __restrict__ lnb, short* __restrict__ z) {
  __shared__ __align__(16) char smem[24320];
  float* Lm = (float*)smem;               // [65][32] — aliased by Pm later
  bf16*  Pm = (bf16*)smem;                // [64][72]
  bf16*  RA = (bf16*)(smem + 9216);       // [64][40]
  bf16*  Kd = (bf16*)(smem + 14336);      // [64][40]
  bf16*  VT = (bf16*)(smem + 19456);      // [32][72]
  bf16*  Eb = VT;                         // [64][32] scratch (dead pre-stage)
  float* bon = (float*)(smem + 24064);    // [64]
  int g = blockIdx.x;
  int bh = g >> 5, c = g & (NC_ - 1);
  int b = bh >> 4, h = bh & 15;
  const int tid = threadIdx.x;
  const int lane = tid & 63, wave = tid >> 6;
  const int tl = lane >> 3;              // 0..7
  const int c4 = (lane & 7) * 4;
  const int fl = lane & 15, q = lane >> 4;
  size_t gbase = (size_t)b * T_ * C_ + (size_t)(c * CL_) * C_ + h * HS_;
  size_t sbase = (size_t)g * STF_;
  const short* ru = (const short*)r;
  const short* ku = (const short*)k;
  const short* vu = (const short*)v;
  const short* eu = (const short*)ee;
  // ee tile -> LDS scratch (8B loads); S fragments from global; r/k/v regs
  #pragma unroll
  for (int it = 0; it < 2; ++it) {
    int e4 = it * 256 + tid;
    int row = e4 >> 3, cc = (e4 & 7) * 4;
    short4v ev = *(const short4v*)&eu[gbase + (size_t)row * C_ + cc];
    *(short4v*)&((short*)Eb)[row * 32 + cc] = ev;
  }
  short8 sh[2] = {}, sl[2] = {};
  if (c != 0) {
    const unsigned short* sb = (const unsigned short*)(st + sbase - STF_);
    #pragma unroll
    for (int nt = 0; nt < 2; ++nt) {
      sh[nt] = *(const short8*)&sb[(nt * 16 + fl) * 32 + q * 8];
      sl[nt] = *(const short8*)&sb[1024 + (nt * 16 + fl) * 32 + q * 8];
    }
  }
  short4v r4[2], k4[2], v4[2];
  #pragma unroll
  for (int it2 = 0; it2 < 2; ++it2) {
    int t = wave * 16 + it2 * 8 + tl;
    size_t gi = gbase + (size_t)t * C_ + c4;
    r4[it2] = *(const short4v*)&ru[gi];
    k4[it2] = *(const short4v*)&ku[gi];
    v4[it2] = *(const short4v*)&vu[gi];
  }
  __syncthreads();
  // serial prefix scan on LDS latency only
  if (tid < 32) {
    float L = 0.f;
    for (int t = 0; t < CL_; ++t) {
      Lm[t * 32 + tid] = L;
      L -= b2f(Eb[t * 32 + tid]);
    }
    Lm[64 * 32 + tid] = L;
  }
  __syncthreads();
  f32x4 u4 = *(const f32x4*)&faaaa[h * HS_ + c4];
  #pragma unroll
  for (int it2 = 0; it2 < 2; ++it2) {
    int t = wave * 16 + it2 * 8 + tl;
    f32x4 Lt4  = *(const f32x4*)&Lm[t * 32 + c4];
    f32x4 Lt14 = *(const f32x4*)&Lm[(t + 1) * 32 + c4];
    short4v ra4, kd4;
    float pb = 0.f;
    #pragma unroll
    for (int j = 0; j < 4; ++j) {
      float rvj = s2f(r4[it2][j]);
      float kvj = s2f(k4[it2][j]);
      ra4[j] = f2s(rvj * __expf(Lt4[j]));
      kd4[j] = f2s(kvj * __expf(-Lt14[j]));
      ((short*)VT)[(c4 + j) * 72 + t] = v4[it2][j];
      pb += rvj * u4[j] * kvj;
    }
    *(short4v*)&((short*)RA)[t * 40 + c4] = ra4;
    *(short4v*)&((short*)Kd)[t * 40 + c4] = kd4;
    pb += __shfl_xor(pb, 1); pb += __shfl_xor(pb, 2); pb += __shfl_xor(pb, 4);
    if ((lane & 7) == 0) bon[t] = pb;
  }
  __syncthreads();
  short8 afr = *(const short8*)(RA + (wave * 16 + fl) * 40 + q * 8);
  f32x4 accY[2] = {};
  #pragma unroll
  for (int nt = 0; nt < 2; ++nt) {
    accY[nt] = __builtin_amdgcn_mfma_f32_16x16x32_bf16(afr, sh[nt], accY[nt], 0, 0, 0);
    accY[nt] = __builtin_amdgcn_mfma_f32_16x16x32_bf16(afr, sl[nt], accY[nt], 0, 0, 0);
  }
  f32x4 accP[4] = {};
  #pragma unroll
  for (int s4 = 0; s4 < 4; ++s4) {
    short8 bk = *(const short8*)(Kd + (s4 * 16 + fl) * 40 + q * 8);
    accP[s4] = __builtin_amdgcn_mfma_f32_16x16x32_bf16(afr, bk, accP[s4], 0, 0, 0);
  }
  // write own Pm band (Lm dead: last read was pre-MFMA barrier)
  #pragma unroll
  for (int s4 = 0; s4 < 4; ++s4)
    #pragma unroll
    for (int rr = 0; rr < 4; ++rr) {
      int t = wave * 16 + q * 4 + rr;
      int s = s4 * 16 + fl;
      float pv = accP[s4][rr];
      float bv = bon[t];
      pv = (s < t) ? pv : ((s == t) ? bv : 0.f);
      Pm[t * 72 + s] = f2b(pv);
    }
  __syncthreads();
  #pragma unroll
  for (int kc = 0; kc < 2; ++kc) {
    short8 ap = *(const short8*)(Pm + (wave * 16 + fl) * 72 + kc * 32 + q * 8);
    #pragma unroll
    for (int nt = 0; nt < 2; ++nt) {
      short8 bv = *(const short8*)(VT + (nt * 16 + fl) * 72 + kc * 32 + q * 8);
      accY[nt] = __builtin_amdgcn_mfma_f32_16x16x32_bf16(ap, bv, accY[nt], 0, 0, 0);
    }
  }
  // fused groupnorm epilogue
  float lw0 = lnw[h * HS_ + fl],      lb0 = lnb[h * HS_ + fl];
  float lw1 = lnw[h * HS_ + 16 + fl], lb1 = lnb[h * HS_ + 16 + fl];
  #pragma unroll
  for (int rr = 0; rr < 4; ++rr) {
    int t = wave * 16 + q * 4 + rr;
    float a0 = accY[0][rr], a1 = accY[1][rr];
    float mu = a0 + a1;
    mu += __shfl_xor(mu, 1); mu += __shfl_xor(mu, 2);
    mu += __shfl_xor(mu, 4); mu += __shfl_xor(mu, 8);
    mu *= (1.f / 32.f);
    float d0 = a0 - mu, d1 = a1 - mu;
    float ss = d0 * d0 + d1 * d1;
    ss += __shfl_xor(ss, 1); ss += __shfl_xor(ss, 2);
    ss += __shfl_xor(ss, 4); ss += __shfl_xor(ss, 8);
    float rs = rsqrtf(ss * (1.f / 32.f) + 1e-5f);
    size_t gi = gbase + (size_t)t * C_;
    float g0 = b2f(gg[gi + fl]);
    float g1 = b2f(gg[gi + 16 + fl]);
    z[gi + fl]      = f2h((d0 * rs * lw0 + lb0) * g0);
    z[gi + 16 + fl] = f2h((d1 * rs * lw1 + lb1) * g1);
  }
}

// ---------------------------------------------------------------------------
extern "C" void kernel_launch(void* const* d_in, const int* in_sizes, int n_in,
                              void* d_out, int out_size, void* d_ws, size_t ws_size,
                              hipStream_t stream) {
  (void)in_sizes; (void)n_in; (void)out_size; (void)ws_size;
  const float* x      = (const float*)d_in[0];
  const float* tmx    = (const float*)d_in[1];
  const float* tmw    = (const float*)d_in[2];
  const float* tmk    = (const float*)d_in[3];
  const float* tmv    = (const float*)d_in[4];
  const float* tmr    = (const float*)d_in[5];
  const float* tmg    = (const float*)d_in[6];
  const float* w1     = (const float*)d_in[7];
  const float* w2     = (const float*)d_in[8];
  const float* tdecay = (const float*)d_in[9];
  const float* wd1    = (const float*)d_in[10];
  const float* wd2    = (const float*)d_in[11];
  const float* faaaa  = (const float*)d_in[12];
  const float* Wr     = (const float*)d_in[13];
  const float* Wk     = (const float*)d_in[14];
  const float* Wv     = (const float*)d_in[15];
  const float* Wg     = (const float*)d_in[16];
  const float* Wo     = (const float*)d_in[17];
  const float* lnw    = (const float*)d_in[18];
  const float* lnb    = (const float*)d_in[19];
  float* out = (float*)d_out;

  // workspace layout — 9 x 16MB slots + st + weights; peak ~168 MB.
  char* w8 = (char*)d_ws;
  const size_t MB = 1024ull * 1024ull;
  short* S0 = (short*)(w8 +  0 * MB);  // xxx -> xw(fp16) -> ee(bf16)
  short* S1 = (short*)(w8 + 16 * MB);  // xk(fp16) -> z(fp16)
  short* S2 = (short*)(w8 + 32 * MB);  // xv(fp16)
  short* S3 = (short*)(w8 + 48 * MB);  // xr(fp16)
  short* S4 = (short*)(w8 + 64 * MB);  // xg(fp16)
  short* S5 = (short*)(w8 + 80 * MB);  // mix5p+h1 -> gb(bf16)
  float* st = (float*)(w8 + 96 * MB);            // 16.5 MB
  char* wreg = w8 + 112 * MB + 512 * 1024;       // weights at 112.5 MB
  short* S6 = (short*)(w8 + 120 * MB); // rb(bf16)
  short* S7 = (short*)(w8 + 136 * MB); // kb(bf16)
  short* S8 = (short*)(w8 + 152 * MB); // vb(bf16)
  short* Wrb  = (short*)(wreg);
  short* Wkb  = Wrb + 2 * WSZ_;
  short* Wvb  = Wkb + 2 * WSZ_;
  short* Wgb  = Wvb + 2 * WSZ_;
  short* Wob  = Wgb + 2 * WSZ_;
  bf16* w1p  = (bf16*)(Wob + 2 * WSZ_);          // [192][512] bf16
  short* wd1p = (short*)(w1p + 192 * 512);       // [64][512] fp16
  bf16* w2p  = (bf16*)(wd1p + 64 * 512);         // [512][192] bf16
  bf16* mix5p = (bf16*)S5;                       // [16384][192], 6 MB
  bf16* h1    = (bf16*)(S5 + (size_t)BT_ * 192); // [16384][64],  2 MB

  // 1. fused prep: xxx (S0) + fp16 weight converts + w1/wd1/w2 transpose
  prep_combo_kernel<<<PREP_N_, 256, 0, stream>>>(
      x, tmx, Wr, Wk, Wv, Wg, Wo, w1, wd1, w2,
      (bf16*)S0, Wrb, Wkb, Wvb, Wgb, Wob, w1p, wd1p, w2p);
  // 2. mix5p = tanh(xxx @ w1p^T)   (bf16 path, BK=64)
  mfma_gemm_kernel<64, 3, 0, 64><<<dim3(128, 3), 256, 0, stream>>>(
      S0, (const short*)w1p, mix5p, 192);
  // 3. all five mixed activations in one MFMA pass -> fp16 (xw over S0)
  mix_mfma_kernel<<<dim3(BT_ / 64, 8), 256, 0, stream>>>(
      mix5p, w2p, x, tmw, tmk, tmv, tmr, tmg, S0, S1, S2, S3, S4);
  // 4. h1 = tanh(xw @ wd1^T) fp16 GEMM;  5. ee = exp(td + h1 @ wd2) (over S0)
  mfma_gemm_kernel<64, 3, 1, 64><<<dim3(128, 1), 256, 0, stream>>>(
      S0, wd1p, h1, 64);
  decay_kernel<<<BT_ / 8, 512, 0, stream>>>(h1, wd2, tdecay, (bf16*)S0);
  // 6. all four fp16 projections in ONE no-LDS barrier-free launch:
  //    xr(S3)->rb(S6), xk(S1)->kb(S7), xv(S2)->vb(S8), xg(S4)->gb(S5,silu)
  proj4_gemm_kernel<<<dim3(BT_ / 64, 1, 4), 512, 0, stream>>>(
      S3, Wrb, (bf16*)S6,  S1, Wkb, (bf16*)S7,
      S2, Wvb, (bf16*)S8,  S4, Wgb, (bf16*)S5);
  // 7-9. chunk-parallel WKV6 scan (4-wave MFMA form, gnorm fused in final)
  wkv_partial_mfma<<<B_ * H_ * NC_, 256, 0, stream>>>(
      (const bf16*)S7, (const bf16*)S8, (const bf16*)S0, st);
  wkv_stitch_kernel<<<B_ * H_, 64, 0, stream>>>(st);
  wkv_final_mfma<<<B_ * H_ * NC_, 256, 0, stream>>>(
      (const bf16*)S6, (const bf16*)S7, (const bf16*)S8, (const bf16*)S0,
      faaaa, st, (const bf16*)S5, lnw, lnb, S1);
  // 10. output projection (fp32) reads fused-gnorm z (S1, fp16), no-LDS
  wo_gemm_kernel<<<dim3(BT_ / 64, 1), 512, 0, stream>>>(S1, Wob, out);
}

// Round 11
// 373.579 us; speedup vs baseline: 1.1999x; 1.1999x over previous
//
#include <hip/hip_runtime.h>
#include <hip/hip_bf16.h>

#define B_ 8
#define T_ 2048
#define C_ 512
#define H_ 16
#define HS_ 32
#define BT_ (B_*T_)   // 16384 tokens
#define CL_ 64        // scan chunk length
#define NC_ (T_/CL_)  // 32 chunks
#define STF_ 1056     // floats per (bh,chunk) state: 1024 S + 32 P
#define WSZ_ 262144   // elements per 512x512 weight (2^18)

typedef __hip_bfloat16 bf16;
typedef __attribute__((ext_vector_type(8))) short short8;
typedef __attribute__((ext_vector_type(4))) short short4v;
typedef __attribute__((ext_vector_type(8))) _Float16 half8;
typedef __attribute__((ext_vector_type(4))) float f32x4;

__device__ __forceinline__ float b2f(bf16 v) { return __bfloat162float(v); }
__device__ __forceinline__ bf16 f2b(float v) { return __float2bfloat16(v); }
// raw-bits helpers for vectorized bf16 handling
__device__ __forceinline__ float s2f(short s) {
  unsigned u = ((unsigned)(unsigned short)s) << 16;
  return __builtin_bit_cast(float, u);
}
__device__ __forceinline__ short f2s(float f) {
  bf16 b = f2b(f);
  return __builtin_bit_cast(short, b);
}
// fp16 raw-bits helpers
__device__ __forceinline__ short f2h(float f) {
  _Float16 h = (_Float16)f;
  return __builtin_bit_cast(short, h);
}

// unified 16x16x32 MFMA over raw short8 operands: FP16=0 -> bf16, 1 -> f16.
template<int FP16>
__device__ __forceinline__ f32x4 mfma16(short8 a, short8 b, f32x4 c) {
  if constexpr (FP16)
    return __builtin_amdgcn_mfma_f32_16x16x32_f16(
        __builtin_bit_cast(half8, a), __builtin_bit_cast(half8, b), c, 0, 0, 0);
  else
    return __builtin_amdgcn_mfma_f32_16x16x32_bf16(a, b, c, 0, 0, 0);
}

// async global->LDS 16B direct copy. LDS dst must be wave-uniform base +
// lane*16 — all call sites use &LDS[tid(+k)] which is.
__device__ __forceinline__ void gl2lds(const void* g, void* l) {
  __builtin_amdgcn_global_load_lds(
      (const __attribute__((address_space(1))) void*)g,
      (__attribute__((address_space(3))) void*)l, 16, 0, 0);
}

// ---------------------------------------------------------------------------
// prep_combo (R10: float4-vectorized hot sections): (a) xxx = x +
// (xshift-x)*maa_x (bf16, 4 elems/thread), (b) fp16 convert of the five
// 512x512 weights (4 elems/thread), (c) transpose+pad w1 -> [192][512] bf16,
// wd1 -> [64][512] fp16, w2 -> [512][192] bf16 (scalar gathers, small).
// ---------------------------------------------------------------------------
__global__ __launch_bounds__(256) void prep_combo_kernel(
    const float* __restrict__ x, const float* __restrict__ tmx,
    const float* __restrict__ Wr, const float* __restrict__ Wk,
    const float* __restrict__ Wv, const float* __restrict__ Wg,
    const float* __restrict__ Wo, const float* __restrict__ w1,
    const float* __restrict__ wd1, const float* __restrict__ w2,
    bf16* __restrict__ xxx, short* __restrict__ Wrb, short* __restrict__ Wkb,
    short* __restrict__ Wvb, short* __restrict__ Wgb, short* __restrict__ Wob,
    bf16* __restrict__ w1p, short* __restrict__ wd1p, bf16* __restrict__ w2p) {
  int idx = blockIdx.x * 256 + threadIdx.x;
  if (idx < BT_ * C_ / 4) {                   // token-shift mix, float4
    int e = idx * 4;
    int c = e & (C_ - 1);
    int t = (e >> 9) & (T_ - 1);
    f32x4 xc = *(const f32x4*)&x[e];
    f32x4 xp = {};
    if (t != 0) xp = *(const f32x4*)&x[e - C_];
    f32x4 tm = *(const f32x4*)&tmx[c];
    short4v o;
    #pragma unroll
    for (int j = 0; j < 4; ++j)
      o[j] = f2s(xc[j] + (xp[j] - xc[j]) * tm[j]);
    *(short4v*)&((short*)xxx)[e] = o;
    return;
  }
  idx -= BT_ * C_ / 4;
  if (idx < 5 * WSZ_ / 4) {                   // weight fp16 convert, float4
    int w = idx >> 16;                        // WSZ_/4 = 65536
    int i = (idx & (WSZ_ / 4 - 1)) * 4;
    const float* src = (w == 0) ? Wr : (w == 1) ? Wk : (w == 2) ? Wv
                     : (w == 3) ? Wg : Wo;
    short* dst = (w == 0) ? Wrb : (w == 1) ? Wkb : (w == 2) ? Wvb
               : (w == 3) ? Wgb : Wob;
    f32x4 s = *(const f32x4*)&src[i];
    short4v o;
    #pragma unroll
    for (int j = 0; j < 4; ++j) o[j] = f2h(s[j]);
    *(short4v*)&dst[i] = o;
    return;
  }
  idx -= 5 * WSZ_ / 4;
  if (idx < 192 * 512) {                      // w1^T padded to 192 rows (bf16)
    int n = idx >> 9, k = idx & (C_ - 1);
    w1p[idx] = f2b(n < 160 ? w1[k * 160 + n] : 0.f);
    return;
  }
  idx -= 192 * 512;
  if (idx < 64 * 512) {                       // wd1^T [64][512] (fp16)
    int n = idx >> 9, k = idx & (C_ - 1);
    wd1p[idx] = f2h(wd1[k * 64 + n]);
    return;
  }
  idx -= 64 * 512;
  {                                           // w2^T padded [512][192] (bf16)
    int c = idx / 192, n = idx - c * 192;     // n = f*32+d
    w2p[idx] = f2b(n < 160 ? w2[(size_t)n * C_ + c] : 0.f);
  }
}
#define PREP_N_ ((BT_*C_/4 + 5*WSZ_/4 + 192*512 + 64*512 + 512*192) / 256) // 10368

// ---------------------------------------------------------------------------
// MFMA GEMM (256 thr): O = act(A @ Bw^T). BM=128. Single-buffer m97 structure
// (best verified form, R7; dbuf/no-LDS/8-wave all regressed R5/R8/R9).
// BKT = K-tile (32 or 64) as BKT/32 consecutive BK=32 sub-tiles.
// FP16: 0 = bf16 operands, 1 = fp16. MODE: 0 bf16; 1 +silu; 2 fp32; 3 +tanh.
// ---------------------------------------------------------------------------
template<int BN, int MODE, int FP16, int BKT>
__global__ __launch_bounds__(256) void mfma_gemm_kernel(
    const short* __restrict__ A, const short* __restrict__ Bw,
    void* __restrict__ O, int N) {
  constexpr int BM = 128;
  constexpr int KC = BKT / 32;               // 32-wide sub-tiles per K-step
  constexpr int AE1 = BM * 32 / 8;           // 512 short8 per sub-tile
  constexpr int BE1 = BN * 32 / 8;
  __shared__ short8 Asm[KC * AE1];
  __shared__ short8 Bsm[KC * BE1];
  const int tid = threadIdx.x;
  const int lane = tid & 63;
  const int wave = tid >> 6;
  const int m0 = blockIdx.x * BM;
  const int n0 = blockIdx.y * BN;
  const int wm = (BN == 128) ? (wave >> 1) * 64 : wave * 32;
  const int wn = (BN == 128) ? (wave & 1) * 64 : 0;
  constexpr int MT = (BN == 128) ? 4 : 2;
  constexpr int NT = 4;
  f32x4 acc[MT][NT] = {};
  const int e0 = tid, e1 = tid + 256;
  const int r0 = ((e0 >> 6) << 4) | (e0 & 15), q0 = (e0 >> 4) & 3;
  const int r1 = ((e1 >> 6) << 4) | (e1 & 15), q1 = (e1 >> 4) & 3;
  const unsigned short* Au = (const unsigned short*)A;
  const unsigned short* Bu = (const unsigned short*)Bw;
  for (int k0 = 0; k0 < C_; k0 += BKT) {
    __syncthreads();   // all ds_reads of previous iteration complete
    #pragma unroll
    for (int kc = 0; kc < KC; ++kc) {
      int kk = k0 + kc * 32;
      gl2lds(&Au[(size_t)(m0 + r0) * C_ + kk + q0 * 8], &Asm[kc * AE1 + e0]);
      gl2lds(&Au[(size_t)(m0 + r1) * C_ + kk + q1 * 8], &Asm[kc * AE1 + e1]);
      gl2lds(&Bu[(size_t)(n0 + r0) * C_ + kk + q0 * 8], &Bsm[kc * BE1 + e0]);
      if constexpr (BN == 128)
        gl2lds(&Bu[(size_t)(n0 + r1) * C_ + kk + q1 * 8], &Bsm[kc * BE1 + e1]);
    }
    __syncthreads();   // implicit vmcnt(0) drain -> LDS tile ready
    #pragma unroll
    for (int kc = 0; kc < KC; ++kc) {
      short8 af[MT], bh[NT];
      #pragma unroll
      for (int mt = 0; mt < MT; ++mt)
        af[mt] = Asm[kc * AE1 + ((wm >> 4) + mt) * 64 + lane];
      #pragma unroll
      for (int nt = 0; nt < NT; ++nt)
        bh[nt] = Bsm[kc * BE1 + ((wn >> 4) + nt) * 64 + lane];
      #pragma unroll
      for (int mt = 0; mt < MT; ++mt)
        #pragma unroll
        for (int nt = 0; nt < NT; ++nt)
          acc[mt][nt] = mfma16<FP16>(af[mt], bh[nt], acc[mt][nt]);
    }
  }
  const int col = lane & 15, qr = lane >> 4;
  #pragma unroll
  for (int mt = 0; mt < MT; ++mt) {
    int mrow = m0 + wm + mt * 16 + qr * 4;
    #pragma unroll
    for (int nt = 0; nt < NT; ++nt) {
      int nc = n0 + wn + nt * 16 + col;
      #pragma unroll
      for (int r = 0; r < 4; ++r) {
        float v = acc[mt][nt][r];
        if (MODE == 1) v = v / (1.f + __expf(-v));
        if (MODE == 3) v = tanhf(v);
        size_t oi = (size_t)(mrow + r) * N + nc;
        if (MODE == 2) ((float*)O)[oi] = v;
        else           ((bf16*)O)[oi] = f2b(v);
      }
    }
  }
}

// ---------------------------------------------------------------------------
// proj4_gemm (R7 best form, reverted): the four independent 512x512 fp16
// projections in one launch (blockIdx.z selects A/Bw/O/silu). Single-buffer
// structure, BK=64 (8 drains). LDS 32KB. 87.4 us measured (R8 bench of R7).
// ---------------------------------------------------------------------------
__global__ __launch_bounds__(256) void proj4_gemm_kernel(
    const short* __restrict__ A0, const short* __restrict__ B0, bf16* __restrict__ O0,
    const short* __restrict__ A1, const short* __restrict__ B1, bf16* __restrict__ O1,
    const short* __restrict__ A2, const short* __restrict__ B2, bf16* __restrict__ O2,
    const short* __restrict__ A3, const short* __restrict__ B3, bf16* __restrict__ O3) {
  constexpr int BM = 128, BN = 128;
  constexpr int KC = 2;                      // BK = 64
  constexpr int AE1 = BM * 32 / 8, BE1 = BN * 32 / 8;
  __shared__ short8 Asm[KC * AE1];
  __shared__ short8 Bsm[KC * BE1];
  const int zz = blockIdx.z;
  const short* A  = (zz == 0) ? A0 : (zz == 1) ? A1 : (zz == 2) ? A2 : A3;
  const short* Bw = (zz == 0) ? B0 : (zz == 1) ? B1 : (zz == 2) ? B2 : B3;
  bf16* O         = (zz == 0) ? O0 : (zz == 1) ? O1 : (zz == 2) ? O2 : O3;
  const bool silu = (zz == 3);
  const int tid = threadIdx.x;
  const int lane = tid & 63;
  const int wave = tid >> 6;
  const int m0 = blockIdx.x * BM;
  const int n0 = blockIdx.y * BN;
  const int wm = (wave >> 1) * 64;
  const int wn = (wave & 1) * 64;
  constexpr int MT = 4, NT = 4;
  f32x4 acc[MT][NT] = {};
  const int e0 = tid, e1 = tid + 256;
  const int r0 = ((e0 >> 6) << 4) | (e0 & 15), q0 = (e0 >> 4) & 3;
  const int r1 = ((e1 >> 6) << 4) | (e1 & 15), q1 = (e1 >> 4) & 3;
  const unsigned short* Au = (const unsigned short*)A;
  const unsigned short* Bu = (const unsigned short*)Bw;
  for (int k0 = 0; k0 < C_; k0 += 64) {
    __syncthreads();
    #pragma unroll
    for (int kc = 0; kc < KC; ++kc) {
      int kk = k0 + kc * 32;
      gl2lds(&Au[(size_t)(m0 + r0) * C_ + kk + q0 * 8], &Asm[kc * AE1 + e0]);
      gl2lds(&Au[(size_t)(m0 + r1) * C_ + kk + q1 * 8], &Asm[kc * AE1 + e1]);
      gl2lds(&Bu[(size_t)(n0 + r0) * C_ + kk + q0 * 8], &Bsm[kc * BE1 + e0]);
      gl2lds(&Bu[(size_t)(n0 + r1) * C_ + kk + q1 * 8], &Bsm[kc * BE1 + e1]);
    }
    __syncthreads();
    #pragma unroll
    for (int kc = 0; kc < KC; ++kc) {
      short8 af[MT], bh[NT];
      #pragma unroll
      for (int mt = 0; mt < MT; ++mt)
        af[mt] = Asm[kc * AE1 + ((wm >> 4) + mt) * 64 + lane];
      #pragma unroll
      for (int nt = 0; nt < NT; ++nt)
        bh[nt] = Bsm[kc * BE1 + ((wn >> 4) + nt) * 64 + lane];
      #pragma unroll
      for (int mt = 0; mt < MT; ++mt)
        #pragma unroll
        for (int nt = 0; nt < NT; ++nt)
          acc[mt][nt] = mfma16<1>(af[mt], bh[nt], acc[mt][nt]);
    }
  }
  const int col = lane & 15, qr = lane >> 4;
  #pragma unroll
  for (int mt = 0; mt < MT; ++mt) {
    int mrow = m0 + wm + mt * 16 + qr * 4;
    #pragma unroll
    for (int nt = 0; nt < NT; ++nt) {
      int nc = n0 + wn + nt * 16 + col;
      #pragma unroll
      for (int r = 0; r < 4; ++r) {
        float v = acc[mt][nt][r];
        if (silu) v = v / (1.f + __expf(-v));
        O[(size_t)(mrow + r) * C_ + nc] = f2b(v);
      }
    }
  }
}

// ---------------------------------------------------------------------------
// mix_mfma (verified round 0): five K=32 GEMMs via MFMA fused with the
// elementwise epilogue x_f = x + (xshift-x)*(tm_f + m_f). Outputs fp16.
// ---------------------------------------------------------------------------
__global__ __launch_bounds__(256) void mix_mfma_kernel(
    const bf16* __restrict__ mix5, const bf16* __restrict__ w2p,
    const float* __restrict__ x,
    const float* __restrict__ tmw, const float* __restrict__ tmk,
    const float* __restrict__ tmv, const float* __restrict__ tmr,
    const float* __restrict__ tmg,
    short* __restrict__ xw, short* __restrict__ xk, short* __restrict__ xv,
    short* __restrict__ xr, short* __restrict__ xg) {
  constexpr int LDP = 200;
  __shared__ __align__(16) unsigned short Asm[64 * LDP];
  __shared__ __align__(16) unsigned short Bsm[64 * LDP];
  const int tid = threadIdx.x;
  const int row0 = blockIdx.x * 64;
  const int col0 = blockIdx.y * 64;
  const unsigned short* Au = (const unsigned short*)mix5;
  const unsigned short* Bu = (const unsigned short*)w2p;
  #pragma unroll
  for (int e0 = 0; e0 < 64 * 20; e0 += 256) {
    int e = e0 + tid;
    int rr = e / 20, p = e - rr * 20;
    *(short8*)&Asm[rr * LDP + p * 8] =
        *(const short8*)&Au[(size_t)(row0 + rr) * 192 + p * 8];
    *(short8*)&Bsm[rr * LDP + p * 8] =
        *(const short8*)&Bu[(size_t)(col0 + rr) * 192 + p * 8];
  }
  __syncthreads();
  const int lane = tid & 63, wave = tid >> 6;
  const int fl = lane & 15, q = lane >> 4;
  short8 af[5];
  #pragma unroll
  for (int f = 0; f < 5; ++f)
    af[f] = *(const short8*)&Asm[(wave * 16 + fl) * LDP + f * 32 + q * 8];
  f32x4 acc[4][5] = {};
  #pragma unroll
  for (int nt = 0; nt < 4; ++nt)
    #pragma unroll
    for (int f = 0; f < 5; ++f) {
      short8 bfr = *(const short8*)&Bsm[(nt * 16 + fl) * LDP + f * 32 + q * 8];
      acc[nt][f] = __builtin_amdgcn_mfma_f32_16x16x32_bf16(
          af[f], bfr, acc[nt][f], 0, 0, 0);
    }
  #pragma unroll
  for (int nt = 0; nt < 4; ++nt) {
    int cc = col0 + nt * 16 + fl;
    float vw = tmw[cc], vk = tmk[cc], vv = tmv[cc], vr = tmr[cc],
          vg = tmg[cc];
    #pragma unroll
    for (int r = 0; r < 4; ++r) {
      int rr = row0 + wave * 16 + q * 4 + r;
      size_t idx = (size_t)rr * C_ + cc;
      float xc = x[idx];
      float xx = (((rr & (T_ - 1)) == 0) ? 0.f : x[idx - C_]) - xc;
      xw[idx] = f2h(xc + xx * (vw + acc[nt][0][r]));
      xk[idx] = f2h(xc + xx * (vk + acc[nt][1][r]));
      xv[idx] = f2h(xc + xx * (vv + acc[nt][2][r]));
      xr[idx] = f2h(xc + xx * (vr + acc[nt][3][r]));
      xg[idx] = f2h(xc + xx * (vg + acc[nt][4][r]));
    }
  }
}

// ---------------------------------------------------------------------------
// decay (unchanged, verified): w = td + h1 @ Wd2 (K=64); ee = exp(w) bf16.
// ---------------------------------------------------------------------------
__global__ __launch_bounds__(512) void decay_kernel(
    const bf16* __restrict__ h1, const float* __restrict__ wd2,
    const float* __restrict__ tdecay, bf16* __restrict__ ee) {
  __shared__ float Hs[8][64];
  int row0 = blockIdx.x * 8;
  {
    int e = threadIdx.x;
    Hs[e >> 6][e & 63] = b2f(h1[(size_t)(row0 + (e >> 6)) * 64 + (e & 63)]);
  }
  __syncthreads();
  int c = threadIdx.x;
  float acc[8] = {0.f,0.f,0.f,0.f,0.f,0.f,0.f,0.f};
  for (int j = 0; j < 64; ++j) {
    float wv = wd2[j * C_ + c];
    #pragma unroll
    for (int r = 0; r < 8; ++r) acc[r] += Hs[r][j] * wv;
  }
  float td = tdecay[c];
  #pragma unroll
  for (int r = 0; r < 8; ++r)
    ee[(size_t)(row0 + r) * C_ + c] = f2b(expf(td + acc[r]));
}

// ---------------------------------------------------------------------------
// WKV6 chunked scan — 4-wave form, vectorized loads (verified round 3).
// ---------------------------------------------------------------------------
__global__ __launch_bounds__(256) void wkv_partial_mfma(
    const bf16* __restrict__ k, const bf16* __restrict__ v,
    const bf16* __restrict__ ee, float* __restrict__ st) {
  __shared__ __align__(16) char smem[17536];
  float* Lm  = (float*)smem;              // [65][32] floats, 8320 B
  bf16*  K2T = (bf16*)(smem + 8320);      // [32][72]
  bf16*  VT  = (bf16*)(smem + 12928);     // [32][72]
  bf16*  Eb  = K2T;                       // [64][32] scratch (dead pre-stage)
  int g = blockIdx.x;
  int bh = g >> 5, c = g & (NC_ - 1);
  int b = bh >> 4, h = bh & 15;
  const int tid = threadIdx.x;
  const int lane = tid & 63, wave = tid >> 6;
  const int tl = lane >> 3;              // 0..7
  const int c4 = (lane & 7) * 4;
  size_t gbase = (size_t)b * T_ * C_ + (size_t)(c * CL_) * C_ + h * HS_;
  const short* ku = (const short*)k;
  const short* vu = (const short*)v;
  const short* eu = (const short*)ee;
  #pragma unroll
  for (int it = 0; it < 2; ++it) {       // ee tile, 8B per thread per iter
    int e4 = it * 256 + tid;             // 0..511
    int row = e4 >> 3, cc = (e4 & 7) * 4;
    short4v ev = *(const short4v*)&eu[gbase + (size_t)row * C_ + cc];
    *(short4v*)&((short*)Eb)[row * 32 + cc] = ev;
  }
  short4v k4[2], v4[2];
  #pragma unroll
  for (int it2 = 0; it2 < 2; ++it2) {
    int t = wave * 16 + it2 * 8 + tl;
    k4[it2] = *(const short4v*)&ku[gbase + (size_t)t * C_ + c4];
    v4[it2] = *(const short4v*)&vu[gbase + (size_t)t * C_ + c4];
  }
  __syncthreads();
  if (tid < 32) {
    float L = 0.f;
    for (int t = 0; t < CL_; ++t) {
      Lm[t * 32 + tid] = L;
      L -= b2f(Eb[t * 32 + tid]);
    }
    Lm[64 * 32 + tid] = L;
  }
  __syncthreads();
  f32x4 Ltot4 = *(const f32x4*)&Lm[64 * 32 + c4];
  #pragma unroll
  for (int it2 = 0; it2 < 2; ++it2) {
    int t = wave * 16 + it2 * 8 + tl;
    f32x4 Lt14 = *(const f32x4*)&Lm[(t + 1) * 32 + c4];
    #pragma unroll
    for (int j = 0; j < 4; ++j) {
      ((short*)K2T)[(c4 + j) * 72 + t] =
          f2s(s2f(k4[it2][j]) * __expf(Ltot4[j] - Lt14[j]));
      ((short*)VT)[(c4 + j) * 72 + t] = v4[it2][j];
    }
  }
  __syncthreads();
  const int fl = lane & 15, q = lane >> 4;
  const int mt = wave >> 1, nt = wave & 1;
  f32x4 accS = {};
  #pragma unroll
  for (int kc = 0; kc < 2; ++kc) {
    short8 av = *(const short8*)(VT + (mt * 16 + fl) * 72 + kc * 32 + q * 8);
    short8 bk = *(const short8*)(K2T + (nt * 16 + fl) * 72 + kc * 32 + q * 8);
    accS = __builtin_amdgcn_mfma_f32_16x16x32_bf16(av, bk, accS, 0, 0, 0);
  }
  size_t sbase = (size_t)g * STF_;
  #pragma unroll
  for (int r = 0; r < 4; ++r)
    st[sbase + (size_t)(mt * 16 + q * 4 + r) * 32 + nt * 16 + fl] = accS[r];
  if (tid < 32) st[sbase + 1024 + tid] = __expf(Lm[64 * 32 + tid]);
}

// ---------------------------------------------------------------------------
// stitch: serial chunk recurrence R = P*R + Sc per (bh), depth-1 software
// pipeline (verified round 3). Incoming state for chunk c emitted bf16 hi/lo
// into dead S-region of slot c-1.
// ---------------------------------------------------------------------------
__global__ __launch_bounds__(64) void wkv_stitch_kernel(float* __restrict__ st) {
  int bh = blockIdx.x;
  int lane = threadIdx.x;
  int i = lane & 31, half = lane >> 5;
  float R[16];
  #pragma unroll
  for (int jj = 0; jj < 16; ++jj) R[jj] = 0.f;
  size_t s0 = (size_t)bh * NC_ * STF_;
  const int off = i * 32 + (half << 4);
  const int poff = 1024 + (half << 4);
  f32x4 Sc[4], Pj[4];
  {
    const f32x4* sp = (const f32x4*)(st + s0 + off);
    const f32x4* pp = (const f32x4*)(st + s0 + poff);
    #pragma unroll
    for (int q = 0; q < 4; ++q) { Sc[q] = sp[q]; Pj[q] = pp[q]; }
  }
  for (int c = 0; c < NC_; ++c) {
    size_t s = s0 + (size_t)c * STF_;
    f32x4 Sn[4], Pn[4];
    if (c + 1 < NC_) {
      const f32x4* sp = (const f32x4*)(st + s + STF_ + off);
      const f32x4* pp = (const f32x4*)(st + s + STF_ + poff);
      #pragma unroll
      for (int q = 0; q < 4; ++q) { Sn[q] = sp[q]; Pn[q] = pp[q]; }
    }
    if (c > 0) {
      __align__(16) short hi16[16], lo16[16];
      #pragma unroll
      for (int jj = 0; jj < 16; ++jj) {
        short hb = f2s(R[jj]);
        hi16[jj] = hb;
        lo16[jj] = f2s(R[jj] - s2f(hb));
      }
      short* sb = (short*)(st + s - STF_);
      *(short8*)&sb[off]         = *(const short8*)&hi16[0];
      *(short8*)&sb[off + 8]     = *(const short8*)&hi16[8];
      *(short8*)&sb[1024 + off]     = *(const short8*)&lo16[0];
      *(short8*)&sb[1024 + off + 8] = *(const short8*)&lo16[8];
    }
    #pragma unroll
    for (int q = 0; q < 4; ++q)
      #pragma unroll
      for (int j = 0; j < 4; ++j)
        R[q * 4 + j] = fmaf(Pj[q][j], R[q * 4 + j], Sc[q][j]);
    if (c + 1 < NC_) {
      #pragma unroll
      for (int q = 0; q < 4; ++q) { Sc[q] = Sn[q]; Pj[q] = Pn[q]; }
    }
  }
}

// ---------------------------------------------------------------------------
// wkv_final: 4-wave + fused groupnorm + vectorized staging (verified round 3).
// S fragments direct from stitched bf16 hi/lo state (slot g-1). z fp16.
// ---------------------------------------------------------------------------
__global__ __launch_bounds__(256) void wkv_final_mfma(
    const bf16* __restrict__ r, const bf16* __restrict__ k,
    const bf16* __restrict__ v, const bf16* __restrict__ ee,
    const float* __restrict__ faaaa, const float* __restrict__ st,
    const bf16* __restrict__ gg, const float* __restrict__ lnw,
    const float* __restrict__ lnb, short* __restrict__ z) {
  __shared__ __align__(16) char smem[24320];
  float* Lm = (float*)smem;               // [65][32] — aliased by Pm later
  bf16*  Pm = (bf16*)smem;                // [64][72]
  bf16*  RA = (bf16*)(smem + 9216);       // [64][40]
  bf16*  Kd = (bf16*)(smem + 14336);      // [64][40]
  bf16*  VT = (bf16*)(smem + 19456);      // [32][72]
  bf16*  Eb = VT;                         // [64][32] scratch (dead pre-stage)
  float* bon = (float*)(smem + 24064);    // [64]
  int g = blockIdx.x;
  int bh = g >> 5, c = g & (NC_ - 1);
  int b = bh >> 4, h = bh & 15;
  const int tid = threadIdx.x;
  const int lane = tid & 63, wave = tid >> 6;
  const int tl = lane >> 3;              // 0..7
  const int c4 = (lane & 7) * 4;
  const int fl = lane & 15, q = lane >> 4;
  size_t gbase = (size_t)b * T_ * C_ + (size_t)(c * CL_) * C_ + h * HS_;
  size_t sbase = (size_t)g * STF_;
  const short* ru = (const short*)r;
  const short* ku = (const short*)k;
  const short* vu = (const short*)v;
  const short* eu = (const short*)ee;
  // ee tile -> LDS scratch (8B loads); S fragments from global; r/k/v regs
  #pragma unroll
  for (int it = 0; it < 2; ++it) {
    int e4 = it * 256 + tid;
    int row = e4 >> 3, cc = (e4 & 7) * 4;
    short4v ev = *(const short4v*)&eu[gbase + (size_t)row * C_ + cc];
    *(short4v*)&((short*)Eb)[row * 32 + cc] = ev;
  }
  short8 sh[2] = {}, sl[2] = {};
  if (c != 0) {
    const unsigned short* sb = (const unsigned short*)(st + sbase - STF_);
    #pragma unroll
    for (int nt = 0; nt < 2; ++nt) {
      sh[nt] = *(const short8*)&sb[(nt * 16 + fl) * 32 + q * 8];
      sl[nt] = *(const short8*)&sb[1024 + (nt * 16 + fl) * 32 + q * 8];
    }
  }
  short4v r4[2], k4[2], v4[2];
  #pragma unroll
  for (int it2 = 0; it2 < 2; ++it2) {
    int t = wave * 16 + it2 * 8 + tl;
    size_t gi = gbase + (size_t)t * C_ + c4;
    r4[it2] = *(const short4v*)&ru[gi];
    k4[it2] = *(const short4v*)&ku[gi];
    v4[it2] = *(const short4v*)&vu[gi];
  }
  __syncthreads();
  // serial prefix scan on LDS latency only
  if (tid < 32) {
    float L = 0.f;
    for (int t = 0; t < CL_; ++t) {
      Lm[t * 32 + tid] = L;
      L -= b2f(Eb[t * 32 + tid]);
    }
    Lm[64 * 32 + tid] = L;
  }
  __syncthreads();
  f32x4 u4 = *(const f32x4*)&faaaa[h * HS_ + c4];
  #pragma unroll
  for (int it2 = 0; it2 < 2; ++it2) {
    int t = wave * 16 + it2 * 8 + tl;
    f32x4 Lt4  = *(const f32x4*)&Lm[t * 32 + c4];
    f32x4 Lt14 = *(const f32x4*)&Lm[(t + 1) * 32 + c4];
    short4v ra4, kd4;
    float pb = 0.f;
    #pragma unroll
    for (int j = 0; j < 4; ++j) {
      float rvj = s2f(r4[it2][j]);
      float kvj = s2f(k4[it2][j]);
      ra4[j] = f2s(rvj * __expf(Lt4[j]));
      kd4[j] = f2s(kvj * __expf(-Lt14[j]));
      ((short*)VT)[(c4 + j) * 72 + t] = v4[it2][j];
      pb += rvj * u4[j] * kvj;
    }
    *(short4v*)&((short*)RA)[t * 40 + c4] = ra4;
    *(short4v*)&((short*)Kd)[t * 40 + c4] = kd4;
    pb += __shfl_xor(pb, 1); pb += __shfl_xor(pb, 2); pb += __shfl_xor(pb, 4);
    if ((lane & 7) == 0) bon[t] = pb;
  }
  __syncthreads();
  short8 afr = *(const short8*)(RA + (wave * 16 + fl) * 40 + q * 8);
  f32x4 accY[2] = {};
  #pragma unroll
  for (int nt = 0; nt < 2; ++nt) {
    accY[nt] = __builtin_amdgcn_mfma_f32_16x16x32_bf16(afr, sh[nt], accY[nt], 0, 0, 0);
    accY[nt] = __builtin_amdgcn_mfma_f32_16x16x32_bf16(afr, sl[nt], accY[nt], 0, 0, 0);
  }
  f32x4 accP[4] = {};
  #pragma unroll
  for (int s4 = 0; s4 < 4; ++s4) {
    short8 bk = *(const short8*)(Kd + (s4 * 16 + fl) * 40 + q * 8);
    accP[s4] = __builtin_amdgcn_mfma_f32_16x16x32_bf16(afr, bk, accP[s4], 0, 0, 0);
  }
  // write own Pm band (Lm dead: last read was pre-MFMA barrier)
  #pragma unroll
  for (int s4 = 0; s4 < 4; ++s4)
    #pragma unroll
    for (int rr = 0; rr < 4; ++rr) {
      int t = wave * 16 + q * 4 + rr;
      int s = s4 * 16 + fl;
      float pv = accP[s4][rr];
      float bv = bon[t];
      pv = (s < t) ? pv : ((s == t) ? bv : 0.f);
      Pm[t * 72 + s] = f2b(pv);
    }
  __syncthreads();
  #pragma unroll
  for (int kc = 0; kc < 2; ++kc) {
    short8 ap = *(const short8*)(Pm + (wave * 16 + fl) * 72 + kc * 32 + q * 8);
    #pragma unroll
    for (int nt = 0; nt < 2; ++nt) {
      short8 bv = *(const short8*)(VT + (nt * 16 + fl) * 72 + kc * 32 + q * 8);
      accY[nt] = __builtin_amdgcn_mfma_f32_16x16x32_bf16(ap, bv, accY[nt], 0, 0, 0);
    }
  }
  // fused groupnorm epilogue
  float lw0 = lnw[h * HS_ + fl],      lb0 = lnb[h * HS_ + fl];
  float lw1 = lnw[h * HS_ + 16 + fl], lb1 = lnb[h * HS_ + 16 + fl];
  #pragma unroll
  for (int rr = 0; rr < 4; ++rr) {
    int t = wave * 16 + q * 4 + rr;
    float a0 = accY[0][rr], a1 = accY[1][rr];
    float mu = a0 + a1;
    mu += __shfl_xor(mu, 1); mu += __shfl_xor(mu, 2);
    mu += __shfl_xor(mu, 4); mu += __shfl_xor(mu, 8);
    mu *= (1.f / 32.f);
    float d0 = a0 - mu, d1 = a1 - mu;
    float ss = d0 * d0 + d1 * d1;
    ss += __shfl_xor(ss, 1); ss += __shfl_xor(ss, 2);
    ss += __shfl_xor(ss, 4); ss += __shfl_xor(ss, 8);
    float rs = rsqrtf(ss * (1.f / 32.f) + 1e-5f);
    size_t gi = gbase + (size_t)t * C_;
    float g0 = b2f(gg[gi + fl]);
    float g1 = b2f(gg[gi + 16 + fl]);
    z[gi + fl]      = f2h((d0 * rs * lw0 + lb0) * g0);
    z[gi + 16 + fl] = f2h((d1 * rs * lw1 + lb1) * g1);
  }
}

// ---------------------------------------------------------------------------
extern "C" void kernel_launch(void* const* d_in, const int* in_sizes, int n_in,
                              void* d_out, int out_size, void* d_ws, size_t ws_size,
                              hipStream_t stream) {
  (void)in_sizes; (void)n_in; (void)out_size; (void)ws_size;
  const float* x      = (const float*)d_in[0];
  const float* tmx    = (const float*)d_in[1];
  const float* tmw    = (const float*)d_in[2];
  const float* tmk    = (const float*)d_in[3];
  const float* tmv    = (const float*)d_in[4];
  const float* tmr    = (const float*)d_in[5];
  const float* tmg    = (const float*)d_in[6];
  const float* w1     = (const float*)d_in[7];
  const float* w2     = (const float*)d_in[8];
  const float* tdecay = (const float*)d_in[9];
  const float* wd1    = (const float*)d_in[10];
  const float* wd2    = (const float*)d_in[11];
  const float* faaaa  = (const float*)d_in[12];
  const float* Wr     = (const float*)d_in[13];
  const float* Wk     = (const float*)d_in[14];
  const float* Wv     = (const float*)d_in[15];
  const float* Wg     = (const float*)d_in[16];
  const float* Wo     = (const float*)d_in[17];
  const float* lnw    = (const float*)d_in[18];
  const float* lnb    = (const float*)d_in[19];
  float* out = (float*)d_out;

  // workspace layout — 9 x 16MB slots + st + weights; peak ~168 MB.
  char* w8 = (char*)d_ws;
  const size_t MB = 1024ull * 1024ull;
  short* S0 = (short*)(w8 +  0 * MB);  // xxx -> xw(fp16) -> ee(bf16)
  short* S1 = (short*)(w8 + 16 * MB);  // xk(fp16) -> z(fp16)
  short* S2 = (short*)(w8 + 32 * MB);  // xv(fp16)
  short* S3 = (short*)(w8 + 48 * MB);  // xr(fp16)
  short* S4 = (short*)(w8 + 64 * MB);  // xg(fp16)
  short* S5 = (short*)(w8 + 80 * MB);  // mix5p+h1 -> gb(bf16)
  float* st = (float*)(w8 + 96 * MB);            // 16.5 MB
  char* wreg = w8 + 112 * MB + 512 * 1024;       // weights at 112.5 MB
  short* S6 = (short*)(w8 + 120 * MB); // rb(bf16)
  short* S7 = (short*)(w8 + 136 * MB); // kb(bf16)
  short* S8 = (short*)(w8 + 152 * MB); // vb(bf16)
  short* Wrb  = (short*)(wreg);
  short* Wkb  = Wrb + 2 * WSZ_;
  short* Wvb  = Wkb + 2 * WSZ_;
  short* Wgb  = Wvb + 2 * WSZ_;
  short* Wob  = Wgb + 2 * WSZ_;
  bf16* w1p  = (bf16*)(Wob + 2 * WSZ_);          // [192][512] bf16
  short* wd1p = (short*)(w1p + 192 * 512);       // [64][512] fp16
  bf16* w2p  = (bf16*)(wd1p + 64 * 512);         // [512][192] bf16
  bf16* mix5p = (bf16*)S5;                       // [16384][192], 6 MB
  bf16* h1    = (bf16*)(S5 + (size_t)BT_ * 192); // [16384][64],  2 MB

  // 1. fused prep (float4-vectorized): xxx (S0) + fp16 weight converts +
  //    w1/wd1/w2 transpose
  prep_combo_kernel<<<PREP_N_, 256, 0, stream>>>(
      x, tmx, Wr, Wk, Wv, Wg, Wo, w1, wd1, w2,
      (bf16*)S0, Wrb, Wkb, Wvb, Wgb, Wob, w1p, wd1p, w2p);
  // 2. mix5p = tanh(xxx @ w1p^T)   (bf16 path, BK=64)
  mfma_gemm_kernel<64, 3, 0, 64><<<dim3(128, 3), 256, 0, stream>>>(
      S0, (const short*)w1p, mix5p, 192);
  // 3. all five mixed activations in one MFMA pass -> fp16 (xw over S0)
  mix_mfma_kernel<<<dim3(BT_ / 64, 8), 256, 0, stream>>>(
      mix5p, w2p, x, tmw, tmk, tmv, tmr, tmg, S0, S1, S2, S3, S4);
  // 4. h1 = tanh(xw @ wd1^T) fp16 GEMM;  5. ee = exp(td + h1 @ wd2) (over S0)
  mfma_gemm_kernel<64, 3, 1, 64><<<dim3(128, 1), 256, 0, stream>>>(
      S0, wd1p, h1, 64);
  decay_kernel<<<BT_ / 8, 512, 0, stream>>>(h1, wd2, tdecay, (bf16*)S0);
  // 6. all four fp16 projections in ONE launch (bf16 outputs), BK=64 (R7 best):
  //    xr(S3)->rb(S6), xk(S1)->kb(S7), xv(S2)->vb(S8), xg(S4)->gb(S5,silu)
  proj4_gemm_kernel<<<dim3(128, 4, 4), 256, 0, stream>>>(
      S3, Wrb, (bf16*)S6,  S1, Wkb, (bf16*)S7,
      S2, Wvb, (bf16*)S8,  S4, Wgb, (bf16*)S5);
  // 7-9. chunk-parallel WKV6 scan (4-wave MFMA form, gnorm fused in final)
  wkv_partial_mfma<<<B_ * H_ * NC_, 256, 0, stream>>>(
      (const bf16*)S7, (const bf16*)S8, (const bf16*)S0, st);
  wkv_stitch_kernel<<<B_ * H_, 64, 0, stream>>>(st);
  wkv_final_mfma<<<B_ * H_ * NC_, 256, 0, stream>>>(
      (const bf16*)S6, (const bf16*)S7, (const bf16*)S8, (const bf16*)S0,
      faaaa, st, (const bf16*)S5, lnw, lnb, S1);
  // 10. output projection (fp32) reads fused-gnorm z (S1, fp16), BK=64
  mfma_gemm_kernel<128, 2, 1, 64><<<dim3(128, 4), 256, 0, stream>>>(
      S1, Wob, out, C_);
}